// Round 4
// baseline (156.779 us; speedup 1.0000x reference)
//
#include <hip/hip_runtime.h>
#include <hip/hip_bf16.h>
#include <math.h>

#define L1_     5248
#define LENRRC_ 129
#define TSTART_ 65
#define NWIN_   5120
#define SWZ(m) ((m) + ((m) >> 3))     // stride-8 reads -> stride-9 -> conflict-free

typedef __attribute__((ext_vector_type(8))) short s16x8;   // 8 bf16 lanes (4 VGPRs)
typedef __attribute__((ext_vector_type(4))) float f32x4;   // MFMA accumulator

__device__ inline ushort bf16_rne(float x) {
    unsigned xb = __float_as_uint(x);
    return (ushort)((xb + 0x7fffu + ((xb >> 16) & 1u)) >> 16);
}

__device__ inline float wave_sum(float v) {
    #pragma unroll
    for (int m = 32; m > 0; m >>= 1) v += __shfl_xor(v, m, 64);
    return v;
}
__device__ inline float wave_max(float v) {
    #pragma unroll
    for (int m = 32; m > 0; m >>= 1) v = fmaxf(v, __shfl_xor(v, m, 64));
    return v;
}

// direct global->LDS 16B staging (dest = wave-uniform base + lane*16)
__device__ inline void gl_lds16(const void* g, void* l) {
    __builtin_amdgcn_global_load_lds(
        (const __attribute__((address_space(1))) unsigned int*)g,
        (__attribute__((address_space(3))) unsigned int*)l, 16, 0, 0);
}

// ---------- fused pack: x->bf16 | W1^T bf16 | W2^T bf16 | (fallback: z=bias) ----------
__global__ __launch_bounds__(256) void pack_k(const float* __restrict__ x,
        const float* __restrict__ W1, const float* __restrict__ W2,
        const float* __restrict__ benc,
        ushort* __restrict__ xb, ushort* __restrict__ w1t, ushort* __restrict__ w2t,
        float* __restrict__ z)
{
    __shared__ ushort tile[64][70];
    const int blk = blockIdx.x, tid = threadIdx.x;
    if (blk < 3072) {                                  // pack x (1024x3072), x4 floats
        int i = blk * 256 + tid;
        float4 v = ((const float4*)x)[i];
        ushort4 h;
        h.x = bf16_rne(v.x); h.y = bf16_rne(v.y);
        h.z = bf16_rne(v.z); h.w = bf16_rne(v.w);
        ((ushort4*)xb)[i] = h;
    } else if (blk < 3840) {                           // transpose W1 / W2 into bf16
        const float* W; ushort* T; int K, N, n0, k0;
        if (blk < 3456) {
            int idx = blk - 3072;                      // grid (8,48)
            W = W1; T = w1t; K = 3072; N = 512;
            n0 = (idx & 7) * 64; k0 = (idx >> 3) * 64;
        } else {
            int idx = blk - 3456;                      // grid (48,8)
            W = W2; T = w2t; K = 512; N = 3072;
            n0 = (idx % 48) * 64; k0 = (idx / 48) * 64;
        }
        const int cr = tid >> 4, cc = (tid & 15) * 4;
        #pragma unroll
        for (int i = 0; i < 4; ++i) {
            int kk = i * 16 + cr;
            float4 v = *(const float4*)&W[(size_t)(k0 + kk) * N + n0 + cc];
            tile[kk][cc]     = bf16_rne(v.x);
            tile[kk][cc + 1] = bf16_rne(v.y);
            tile[kk][cc + 2] = bf16_rne(v.z);
            tile[kk][cc + 3] = bf16_rne(v.w);
        }
        __syncthreads();
        #pragma unroll
        for (int i = 0; i < 4; ++i) {
            int nn = i * 16 + cr;
            ushort4 h;
            h.x = tile[cc][nn]; h.y = tile[cc + 1][nn];
            h.z = tile[cc + 2][nn]; h.w = tile[cc + 3][nn];
            *(ushort4*)&T[(size_t)(n0 + nn) * K + k0 + cc] = h;
        }
    } else {                                           // fallback only: init z with bias
        int i = (blk - 3840) * 256 + tid;              // 524288 total
        z[i] = benc[i & 511];
    }
}

// ---------- gemm1: 64x128xBK64, global_load_lds + XOR-swizzle, SK=16 partial panels ----------
__global__ __launch_bounds__(256) void gemm1_k(const ushort* __restrict__ Ab,
        const ushort* __restrict__ Bb, float* __restrict__ C, int M, int N, int K,
        int partial, int nsp)
{
    __shared__ __attribute__((aligned(16))) ushort Asl[64 * 64];    // 8 KB, linear
    __shared__ __attribute__((aligned(16))) ushort Bsl[128 * 64];   // 16 KB, linear
    const int tid = threadIdx.x;
    const int lane = tid & 63, wave = tid >> 6;
    const int wm = (wave >> 1) * 32, wn = (wave & 1) * 64;
    const int m0 = blockIdx.y * 64, n0 = blockIdx.x * 128;
    const int kch = K / nsp, kbeg = blockIdx.z * kch, kend = kbeg + kch;
    const int fm = lane & 15, q = lane >> 4;
    f32x4 acc[2][4] = {};

    // per-lane staging coords: chunk c -> (row, kb) with kb inverse-swizzled,
    // so linear LDS dest holds the XOR-swizzled layout (rule 21: both-sides)
    int arow[2], akb[2], brow[4], bkb[4];
    #pragma unroll
    for (int j = 0; j < 2; ++j) {
        int c = ((wave * 2 + j) << 6) + lane;
        arow[j] = c >> 3; akb[j] = (c & 7) ^ (arow[j] & 7);
    }
    #pragma unroll
    for (int j = 0; j < 4; ++j) {
        int c = ((wave * 4 + j) << 6) + lane;
        brow[j] = c >> 3; bkb[j] = (c & 7) ^ (brow[j] & 7);
    }

    for (int kt = kbeg; kt < kend; kt += 64) {
        #pragma unroll
        for (int j = 0; j < 2; ++j)                    // A 64x64 = 8 segments
            gl_lds16(&Ab[(size_t)(m0 + arow[j]) * K + kt + akb[j] * 8],
                     &Asl[(wave * 2 + j) << 9]);
        #pragma unroll
        for (int j = 0; j < 4; ++j)                    // B 128x64 = 16 segments
            gl_lds16(&Bb[(size_t)(n0 + brow[j]) * K + kt + bkb[j] * 8],
                     &Bsl[(wave * 4 + j) << 9]);
        __syncthreads();                               // vmcnt(0) drain inserted here
        #pragma unroll
        for (int ks = 0; ks < 2; ++ks) {
            s16x8 a[2], b[4];
            #pragma unroll
            for (int mf = 0; mf < 2; ++mf) {
                int r = wm + mf * 16 + fm;
                a[mf] = *(const s16x8*)&Asl[(r << 6) + ((((ks << 2) + q) ^ (r & 7)) << 3)];
            }
            #pragma unroll
            for (int nf = 0; nf < 4; ++nf) {
                int r = wn + nf * 16 + fm;
                b[nf] = *(const s16x8*)&Bsl[(r << 6) + ((((ks << 2) + q) ^ (r & 7)) << 3)];
            }
            #pragma unroll
            for (int mf = 0; mf < 2; ++mf)
                #pragma unroll
                for (int nf = 0; nf < 4; ++nf)
                    acc[mf][nf] = __builtin_amdgcn_mfma_f32_16x16x32_bf16(a[mf], b[nf], acc[mf][nf], 0, 0, 0);
        }
        __syncthreads();
    }

    if (partial) {                                     // deterministic per-split panel
        float* Cs = C + (size_t)blockIdx.z * ((size_t)M * N);
        #pragma unroll
        for (int mf = 0; mf < 2; ++mf)
            #pragma unroll
            for (int nf = 0; nf < 4; ++nf)
                #pragma unroll
                for (int r = 0; r < 4; ++r) {
                    int m = m0 + wm + mf * 16 + q * 4 + r;
                    int n = n0 + wn + nf * 16 + fm;
                    Cs[(size_t)m * N + n] = acc[mf][nf][r];
                }
    } else {                                           // fallback: atomic accumulate
        #pragma unroll
        for (int mf = 0; mf < 2; ++mf)
            #pragma unroll
            for (int nf = 0; nf < 4; ++nf)
                #pragma unroll
                for (int r = 0; r < 4; ++r) {
                    int m = m0 + wm + mf * 16 + q * 4 + r;
                    int n = n0 + wn + nf * 16 + fm;
                    atomicAdd(&C[(size_t)m * N + n], acc[mf][nf][r]);
                }
    }
}

// ---------- gemm2: 64x64xBK64, global_load_lds + XOR-swizzle, + bias, fused PAPR loss ----------
__global__ __launch_bounds__(256) void gemm2_k(const ushort* __restrict__ Ab,
        const ushort* __restrict__ Bb, const float* __restrict__ bias,
        const float* __restrict__ papr, float* __restrict__ C,
        float* __restrict__ out_loss, int M, int N, int K)
{
    __shared__ __attribute__((aligned(16))) ushort Asl[64 * 64];
    __shared__ __attribute__((aligned(16))) ushort Bsl[64 * 64];
    __shared__ float red[4];
    const int tid = threadIdx.x;
    const int lane = tid & 63, wave = tid >> 6;
    const int wm = (wave >> 1) * 32, wn = (wave & 1) * 32;
    const int m0 = blockIdx.y * 64, n0 = blockIdx.x * 64;
    const int fm = lane & 15, q = lane >> 4;
    f32x4 acc[2][2] = {};

    int srow[2], skb[2];
    #pragma unroll
    for (int j = 0; j < 2; ++j) {
        int c = ((wave * 2 + j) << 6) + lane;
        srow[j] = c >> 3; skb[j] = (c & 7) ^ (srow[j] & 7);
    }

    for (int kt = 0; kt < K; kt += 64) {
        #pragma unroll
        for (int j = 0; j < 2; ++j) {
            gl_lds16(&Ab[(size_t)(m0 + srow[j]) * K + kt + skb[j] * 8],
                     &Asl[(wave * 2 + j) << 9]);
            gl_lds16(&Bb[(size_t)(n0 + srow[j]) * K + kt + skb[j] * 8],
                     &Bsl[(wave * 2 + j) << 9]);
        }
        __syncthreads();
        #pragma unroll
        for (int ks = 0; ks < 2; ++ks) {
            s16x8 a[2], b[2];
            #pragma unroll
            for (int mf = 0; mf < 2; ++mf) {
                int r = wm + mf * 16 + fm;
                a[mf] = *(const s16x8*)&Asl[(r << 6) + ((((ks << 2) + q) ^ (r & 7)) << 3)];
            }
            #pragma unroll
            for (int nf = 0; nf < 2; ++nf) {
                int r = wn + nf * 16 + fm;
                b[nf] = *(const s16x8*)&Bsl[(r << 6) + ((((ks << 2) + q) ^ (r & 7)) << 3)];
            }
            #pragma unroll
            for (int mf = 0; mf < 2; ++mf)
                #pragma unroll
                for (int nf = 0; nf < 2; ++nf)
                    acc[mf][nf] = __builtin_amdgcn_mfma_f32_16x16x32_bf16(a[mf], b[nf], acc[mf][nf], 0, 0, 0);
        }
        __syncthreads();
    }

    #pragma unroll
    for (int mf = 0; mf < 2; ++mf)
        #pragma unroll
        for (int nf = 0; nf < 2; ++nf)
            #pragma unroll
            for (int r = 0; r < 4; ++r) {
                int m = m0 + wm + mf * 16 + q * 4 + r;
                int n = n0 + wn + nf * 16 + fm;
                C[(size_t)m * N + n] = acc[mf][nf][r] + bias[n];
            }

    if (blockIdx.x == 0 && blockIdx.y == 0) {          // fused PAPR loss
        float s = 0.f;
        for (int i = tid; i < 1024; i += 256) { float v = papr[i] - 8.f; s += v > 0.f ? v : 0.f; }
        s = wave_sum(s);
        if (lane == 0) red[wave] = s;
        __syncthreads();
        if (tid == 0) *out_loss = (red[0] + red[1] + red[2] + red[3]) * (1.f / 1024.f);
    }
}

// ---------- megakernel: 512 threads, pair-split DFT chains, shfl-folded P7a ----------
__global__ __launch_bounds__(512, 8) void mega_k(const float* __restrict__ z,
        const float* __restrict__ benc,
        const float* __restrict__ rrc, const float* __restrict__ awgn,
        const int* __restrict__ slocp, ushort* __restrict__ y5b,
        float* __restrict__ papr, float* __restrict__ out_papr, int nsp)
{
    __shared__ float  zl[512];
    __shared__ float2 frfi[8][32];
    __shared__ float2 trti[672];       // [0..15]=0 | data [16..655] | [656..671]=0 ; reused as dp/dm after P6
    __shared__ float  hl[132];
    __shared__ float  csl[16], ssl[16];
    __shared__ float2 cs64[64];
    __shared__ float2 gcs[130];
    __shared__ float  dxr[SWZ(L1_ - 1) + 1];
    __shared__ float  red[8], red2[8];

    const int b = blockIdx.x, tid = threadIdx.x;
    const int lane = tid & 63, wv = tid >> 6;
    const int sloc = *slocp;

    // ---- tables ----
    if (tid < 64) {
        float ang = 0.09817477042468103f * (float)tid;   // 2pi/64
        float s, c; sincosf(ang, &s, &c);
        cs64[tid] = make_float2(c, s);
    }
    if (tid >= 64 && tid < 80) {
        int t = tid - 64;
        float ang = 1.9634954084936207f * (float)t;      // 2pi*5/16
        float s, c; sincosf(ang, &s, &c);
        csl[t] = 1.4142135623730951f * c; ssl[t] = 1.4142135623730951f * s;
    }
    if (tid >= 96 && tid < 128) {                        // trti zero pads
        int t = tid - 96;
        int idx = (t < 16) ? t : (640 + t);              // [0..15] and [656..671]
        trti[idx] = make_float2(0.f, 0.f);
    }
    if (tid >= 256 && tid < 256 + LENRRC_) hl[tid - 256] = rrc[tid - 256];

    // ---- z row: bias + sum of split-K partial panels (or prereduced fallback) ----
    float v0;
    if (nsp) {
        v0 = benc[tid];
        const float* zp = z + (size_t)b * 512;
        for (int s = 0; s < nsp; ++s)
            v0 += zp[(size_t)s * 524288 + tid];
    } else {
        v0 = z[(size_t)b * 512 + tid];
    }
    __syncthreads();

    // ---- gcs: carrier folded into RRC taps ----
    if (tid < LENRRC_) {
        int neg = (16 - (tid & 15)) & 15;                // (-d) & 15
        gcs[tid] = make_float2(hl[tid] * csl[neg], hl[tid] * ssl[neg]);
    }

    // ---- power norm (single pass: S, Q; ddof=1) ----
    {
        float S = wave_sum(v0);
        float Q = wave_sum(v0 * v0);
        if (lane == 0) { red[wv] = S; red2[wv] = Q; }
    }
    __syncthreads();
    {
        float S = 0.f, Q = 0.f;
        #pragma unroll
        for (int w = 0; w < 8; ++w) { S += red[w]; Q += red2[w]; }
        float mean = S * (1.f / 512.f);
        float var = (Q - S * mean) * (1.f / 511.f);
        float inv = 1.f / (sqrtf(var) + 1e-8f);
        zl[tid] = (v0 - mean) * inv;
    }
    __syncthreads();

    // ---- P1: DFT32 (+fftshift folded), pair-split (lane 2t/2t+1 share output t) ----
    {
        int out = tid >> 1, h = tid & 1;
        int s = out >> 5, kk = out & 31;
        int kk2 = (kk + 16) & 31;
        float sr = 0.f, si = 0.f;
        int t2 = (16 * h * kk2) & 31;
        int qb = s * 32 + 16 * h;
        #pragma unroll 4
        for (int q = 0; q < 16; ++q) {
            float2 w = cs64[2 * t2];
            float2 c = *(const float2*)&zl[(qb + q) * 2];
            sr += c.x * w.x + c.y * w.y;                 // * e^{-i ang}
            si += c.y * w.x - c.x * w.y;
            t2 = (t2 + kk2) & 31;
        }
        sr += __shfl_xor(sr, 1, 64);
        si += __shfl_xor(si, 1, 64);
        if (h == 0)
            frfi[s][kk] = make_float2(sr * 0.1767766952966369f, si * 0.1767766952966369f);
    }
    __syncthreads();

    // ---- P2: IDFT64 + CP, n/(n+32) fold + pair-split over k ----
    {
        int out = tid >> 1, h = tid & 1;
        int s = out >> 5, n = out & 31;
        float er = 0.f, ei = 0.f, or_ = 0.f, oi = 0.f;   // k-even / k-odd partial sums
        int t = ((sloc + 16 * h) * n) & 63;
        int kb = 16 * h;
        #pragma unroll 2
        for (int k = 0; k < 16; k += 2) {
            float2 w = cs64[t];
            float2 f = frfi[s][kb + k];
            er += f.x * w.x - f.y * w.y;                 // * e^{+i ang}
            ei += f.y * w.x + f.x * w.y;
            t = (t + n) & 63;
            w = cs64[t];
            f = frfi[s][kb + k + 1];
            or_ += f.x * w.x - f.y * w.y;
            oi  += f.y * w.x + f.x * w.y;
            t = (t + n) & 63;
        }
        er += __shfl_xor(er, 1, 64);  ei += __shfl_xor(ei, 1, 64);
        or_ += __shfl_xor(or_, 1, 64); oi += __shfl_xor(oi, 1, 64);
        if (h == 0) {
            float sgn = (sloc & 1) ? -1.f : 1.f;
            float dr0 = (er + or_) * 0.125f, di0 = (ei + oi) * 0.125f;        // d[n]
            float dr1 = sgn * (er - or_) * 0.125f, di1 = sgn * (ei - oi) * 0.125f; // d[n+32]
            int base = s * 80;                           // data at [base+32 .. base+95]
            trti[base + 32 + n] = make_float2(dr0, di0);
            trti[base + 64 + n] = make_float2(dr1, di1);
            if (n >= 16) trti[base + n] = make_float2(dr1, di1);   // CP
        }
    }
    __syncthreads();

    // ---- P3: upsample x8 + RRC polyphase + carrier, task-split (a,g) ----
    float ss = 0.f;
    for (int tsk = tid; tsk < 1312; tsk += 512) {
        int a = tsk >> 1, g = tsk & 1;
        float accr[4] = {}, acci[4] = {};
        #pragma unroll 4
        for (int d = 0; d < 16; ++d) {
            float2 tv = trti[16 + a - d];                // zero-padded: no bounds check
            #pragma unroll
            for (int r = 0; r < 4; ++r) {
                float h = hl[g * 4 + r + 8 * d];
                accr[r] += tv.x * h; acci[r] += tv.y * h;
            }
        }
        if (g == 0) {                                    // d=16, tap 128, r=0 only
            float2 tv = trti[a];                         // 16 + a - 16
            float h = hl[128];
            accr[0] += tv.x * h; acci[0] += tv.y * h;
        }
        int cb = (a & 1) * 8;
        #pragma unroll
        for (int r = 0; r < 4; ++r) {
            int rr = g * 4 + r;
            float v = accr[r] * csl[cb + rr] - acci[r] * ssl[cb + rr];
            dxr[SWZ(a * 8 + rr)] = v;
            ss += v * v;
        }
    }
    ss = wave_sum(ss);
    if (lane == 0) red[wv] = ss;
    __syncthreads();
    float thr;
    {
        float S = 0.f;
        #pragma unroll
        for (int w = 0; w < 8; ++w) S += red[w];
        thr = 1.2f * sqrtf(S / (float)L1_);
    }
    __syncthreads();

    // ---- P5: clip + PAPR window stats + AWGN (in place), float4 x4-wide ----
    float pmax = 0.f, psum = 0.f;
    {
        const float4* ag = (const float4*)&awgn[(size_t)b * L1_];
        for (int ii = tid; ii < 1312; ii += 512) {       // 1312*4 = 5248
            float4 aw = ag[ii];
            int i = ii * 4;
            #pragma unroll
            for (int e = 0; e < 4; ++e) {
                int idx = i + e;
                float x = dxr[SWZ(idx)];
                float ax = fabsf(x);
                float over = fmaxf(ax - thr, 0.f);
                float y = (1.f - over / (ax + 1e-8f)) * x;
                if (idx >= TSTART_ && idx < TSTART_ + NWIN_) {
                    float p = y * y; psum += p; pmax = fmaxf(pmax, p);
                }
                float awv = (e == 0) ? aw.x : (e == 1) ? aw.y : (e == 2) ? aw.z : aw.w;
                dxr[SWZ(idx)] = y + awv;
            }
        }
    }
    psum = wave_sum(psum); pmax = wave_max(pmax);
    if (lane == 0) { red[wv] = psum; red2[wv] = pmax; }
    __syncthreads();
    if (tid == 0) {
        float sum = 0.f, mx = 0.f;
        #pragma unroll
        for (int w = 0; w < 8; ++w) { sum += red[w]; mx = fmaxf(mx, red2[w]); }
        float pdb = 10.f * log10f(mx / (sum / (float)NWIN_));
        papr[b] = pdb;
        out_papr[b] = pdb;
    }
    __syncthreads();     // also guarantees all P5 dxr writes visible before P6

    // ---- P6: matched RRC filter + in-wave +/- fold (replaces wrli + P7a) ----
    {
        int s = wv, n = lane;                            // 8 waves x 64 outputs
        int T0 = s * 80 + n + 32;                        // Nf/8
        int base = 9 * T0;                               // SWZ(Nf)
        float ar = 0.f, ai = 0.f;
        int db = 0;
        #pragma unroll 4
        for (int e = 0; e < 16; ++e) {
            #pragma unroll
            for (int u = 0; u < 8; ++u) {
                int off = (u == 0) ? 0 : (u + 1);
                float2 g = gcs[db + u];
                float va = dxr[base - off];
                ar += va * g.x; ai += va * g.y;
            }
            base -= 9; db += 8;
        }
        {
            float2 g = gcs[128];
            float va = dxr[base];
            ar += va * g.x; ai += va * g.y;
        }
        bool odd = (n & 1);
        float dx = odd ? -ar : ar;                       // d[n].re
        float dy = odd ? ai : -ai;                       // d[n].im
        float px = __shfl_xor(dx, 32, 64);
        float py = __shfl_xor(dy, 32, 64);
        // lanes 0..31: dp = d[n]+d[n+32] -> trti[s*32+n]
        // lanes 32..63: dm = d[n-32]-d[n] -> trti[256+s*32+(n-32)]
        float2 res = (n < 32) ? make_float2(dx + px, dy + py)
                              : make_float2(px - dx, py - dy);
        trti[((n >> 5) * 256) + s * 32 + (n & 31)] = res;
    }
    __syncthreads();

    // ---- P7: DFT64 -> band select -> fftshift, n-fold + pair-split ----
    {
        int out = tid >> 1, h = tid & 1;
        int s = out >> 5, kk = out & 31;
        int f = sloc + kk;
        const float2* dsel = &trti[((f & 1) ? 256 : 0) + s * 32 + 16 * h];
        float vr = 0.f, vi = 0.f;
        int t = (16 * h * f) & 63;
        #pragma unroll 4
        for (int n = 0; n < 16; ++n) {
            float2 w = cs64[t];
            float2 d = dsel[n];
            vr += d.x * w.x + d.y * w.y;                 // * e^{-i ang}
            vi += d.y * w.x - d.x * w.y;
            t = (t + f) & 63;
        }
        vr += __shfl_xor(vr, 1, 64);
        vi += __shfl_xor(vi, 1, 64);
        if (h == 0) {
            int ksh = (kk + 16) & 31;
            frfi[s][ksh] = make_float2(vr * 0.125f, vi * 0.125f);
        }
    }
    __syncthreads();

    // ---- P8: IDFT32 -> y5 single bf16 plane, pair-split ----
    {
        int out = tid >> 1, h = tid & 1;
        int s = out >> 5, q2 = out & 31;
        float ur = 0.f, ui = 0.f;
        int t2 = (16 * h * q2) & 31;
        int kb = 16 * h;
        #pragma unroll 4
        for (int k = 0; k < 16; ++k) {
            float2 w = cs64[2 * t2];
            float2 f = frfi[s][kb + k];
            ur += f.x * w.x - f.y * w.y;                 // * e^{+i ang}
            ui += f.y * w.x + f.x * w.y;
            t2 = (t2 + q2) & 31;
        }
        ur += __shfl_xor(ur, 1, 64);
        ui += __shfl_xor(ui, 1, 64);
        if (h == 0) {
            ur *= 0.1767766952966369f; ui *= 0.1767766952966369f;
            ushort2 hv; hv.x = bf16_rne(ur); hv.y = bf16_rne(ui);
            *(ushort2*)&y5b[(size_t)b * 512 + (s * 32 + q2) * 2] = hv;
        }
    }
}

extern "C" void kernel_launch(void* const* d_in, const int* in_sizes, int n_in,
                              void* d_out, int out_size, void* d_ws, size_t ws_size,
                              hipStream_t stream) {
    const float* x    = (const float*)d_in[0];
    const float* Wenc = (const float*)d_in[1];
    const float* benc = (const float*)d_in[2];
    const float* Wdec = (const float*)d_in[3];
    const float* bdec = (const float*)d_in[4];
    const float* rrc  = (const float*)d_in[5];
    const float* awgn = (const float*)d_in[6];
    const int* sloc   = (const int*)d_in[7];
    float* out = (float*)d_out;

    char* wsb = (char*)d_ws;
    ushort* xb   = (ushort*)wsb;                     wsb += (size_t)1024 * 3072 * 2;
    ushort* w1t  = (ushort*)wsb;                     wsb += (size_t)512 * 3072 * 2;
    ushort* w2t  = (ushort*)wsb;                     wsb += (size_t)3072 * 512 * 2;
    ushort* y5b  = (ushort*)wsb;                     wsb += (size_t)1024 * 512 * 2;
    float*  papr = (float*)wsb;                      wsb += 1024 * 4;
    float*  zbuf = (float*)wsb;                      // partial: 16 x 1024x512 f32 (33.5 MB)
                                                     // fallback: 1024x512 f32 (2.1 MB)
    size_t head = (size_t)((char*)zbuf - (char*)d_ws);
    const int SK = 16;
    int partial = (ws_size >= head + (size_t)SK * 1024 * 512 * 4) ? 1 : 0;

    float* out_papr = out + (size_t)1024 * 3072;
    float* out_loss = out_papr + 1024;

    pack_k<<<partial ? 3840 : 5888, 256, 0, stream>>>(x, Wenc, Wdec, benc, xb, w1t, w2t, zbuf);
    gemm1_k<<<dim3(4, 16, partial ? SK : 8), 256, 0, stream>>>(xb, w1t, zbuf, 1024, 512, 3072,
                                                               partial, partial ? SK : 8);
    mega_k<<<1024, 512, 0, stream>>>(zbuf, benc, rrc, awgn, sloc, y5b, papr, out_papr,
                                     partial ? SK : 0);
    gemm2_k<<<dim3(48, 16, 1), 256, 0, stream>>>(y5b, w2t, bdec, papr, out, out_loss, 1024, 3072, 512);
}

// Round 5
// 147.738 us; speedup vs baseline: 1.0612x; 1.0612x over previous
//
#include <hip/hip_runtime.h>
#include <hip/hip_bf16.h>
#include <math.h>

#define L1_     5248
#define LENRRC_ 129
#define TSTART_ 65
#define NWIN_   5120
#define SWZ(m) ((m) + ((m) >> 3))     // stride-8 reads -> stride-9 -> conflict-free

typedef __attribute__((ext_vector_type(8))) short s16x8;   // 8 bf16 lanes (4 VGPRs)
typedef __attribute__((ext_vector_type(4))) float f32x4;   // MFMA accumulator

__device__ inline ushort bf16_rne(float x) {
    unsigned xb = __float_as_uint(x);
    return (ushort)((xb + 0x7fffu + ((xb >> 16) & 1u)) >> 16);
}

__device__ inline float wave_sum(float v) {
    #pragma unroll
    for (int m = 32; m > 0; m >>= 1) v += __shfl_xor(v, m, 64);
    return v;
}
__device__ inline float wave_max(float v) {
    #pragma unroll
    for (int m = 32; m > 0; m >>= 1) v = fmaxf(v, __shfl_xor(v, m, 64));
    return v;
}

// direct global->LDS 16B staging (dest = wave-uniform base + lane*16)
__device__ inline void gl_lds16(const void* g, void* l) {
    __builtin_amdgcn_global_load_lds(
        (const __attribute__((address_space(1))) unsigned int*)g,
        (__attribute__((address_space(3))) unsigned int*)l, 16, 0, 0);
}

// ---------- fused pack: x->bf16 | W1^T bf16 | W2^T bf16 | (fallback: z=bias) ----------
__global__ __launch_bounds__(256) void pack_k(const float* __restrict__ x,
        const float* __restrict__ W1, const float* __restrict__ W2,
        const float* __restrict__ benc,
        ushort* __restrict__ xb, ushort* __restrict__ w1t, ushort* __restrict__ w2t,
        float* __restrict__ z)
{
    __shared__ ushort tile[64][70];
    const int blk = blockIdx.x, tid = threadIdx.x;
    if (blk < 3072) {                                  // pack x (1024x3072), x4 floats
        int i = blk * 256 + tid;
        float4 v = ((const float4*)x)[i];
        ushort4 h;
        h.x = bf16_rne(v.x); h.y = bf16_rne(v.y);
        h.z = bf16_rne(v.z); h.w = bf16_rne(v.w);
        ((ushort4*)xb)[i] = h;
    } else if (blk < 3840) {                           // transpose W1 / W2 into bf16
        const float* W; ushort* T; int K, N, n0, k0;
        if (blk < 3456) {
            int idx = blk - 3072;                      // grid (8,48)
            W = W1; T = w1t; K = 3072; N = 512;
            n0 = (idx & 7) * 64; k0 = (idx >> 3) * 64;
        } else {
            int idx = blk - 3456;                      // grid (48,8)
            W = W2; T = w2t; K = 512; N = 3072;
            n0 = (idx % 48) * 64; k0 = (idx / 48) * 64;
        }
        const int cr = tid >> 4, cc = (tid & 15) * 4;
        #pragma unroll
        for (int i = 0; i < 4; ++i) {
            int kk = i * 16 + cr;
            float4 v = *(const float4*)&W[(size_t)(k0 + kk) * N + n0 + cc];
            tile[kk][cc]     = bf16_rne(v.x);
            tile[kk][cc + 1] = bf16_rne(v.y);
            tile[kk][cc + 2] = bf16_rne(v.z);
            tile[kk][cc + 3] = bf16_rne(v.w);
        }
        __syncthreads();
        #pragma unroll
        for (int i = 0; i < 4; ++i) {
            int nn = i * 16 + cr;
            ushort4 h;
            h.x = tile[cc][nn]; h.y = tile[cc + 1][nn];
            h.z = tile[cc + 2][nn]; h.w = tile[cc + 3][nn];
            *(ushort4*)&T[(size_t)(n0 + nn) * K + k0 + cc] = h;
        }
    } else {                                           // fallback only: init z with bias
        int i = (blk - 3840) * 256 + tid;              // 524288 total
        z[i] = benc[i & 511];
    }
}

// ---------- gemm1: 64x128xBK64, global_load_lds + XOR-swizzle, SK=8 partial panels ----------
__global__ __launch_bounds__(256) void gemm1_k(const ushort* __restrict__ Ab,
        const ushort* __restrict__ Bb, float* __restrict__ C, int M, int N, int K,
        int partial)
{
    __shared__ __attribute__((aligned(16))) ushort Asl[64 * 64];    // 8 KB, linear
    __shared__ __attribute__((aligned(16))) ushort Bsl[128 * 64];   // 16 KB, linear
    const int tid = threadIdx.x;
    const int lane = tid & 63, wave = tid >> 6;
    const int wm = (wave >> 1) * 32, wn = (wave & 1) * 64;
    const int m0 = blockIdx.y * 64, n0 = blockIdx.x * 128;
    const int kch = K / 8, kbeg = blockIdx.z * kch, kend = kbeg + kch;
    const int fm = lane & 15, q = lane >> 4;
    f32x4 acc[2][4] = {};

    int arow[2], akb[2], brow[4], bkb[4];
    #pragma unroll
    for (int j = 0; j < 2; ++j) {
        int c = ((wave * 2 + j) << 6) + lane;
        arow[j] = c >> 3; akb[j] = (c & 7) ^ (arow[j] & 7);
    }
    #pragma unroll
    for (int j = 0; j < 4; ++j) {
        int c = ((wave * 4 + j) << 6) + lane;
        brow[j] = c >> 3; bkb[j] = (c & 7) ^ (brow[j] & 7);
    }

    for (int kt = kbeg; kt < kend; kt += 64) {
        #pragma unroll
        for (int j = 0; j < 2; ++j)                    // A 64x64 = 8 segments
            gl_lds16(&Ab[(size_t)(m0 + arow[j]) * K + kt + akb[j] * 8],
                     &Asl[(wave * 2 + j) << 9]);
        #pragma unroll
        for (int j = 0; j < 4; ++j)                    // B 128x64 = 16 segments
            gl_lds16(&Bb[(size_t)(n0 + brow[j]) * K + kt + bkb[j] * 8],
                     &Bsl[(wave * 4 + j) << 9]);
        __syncthreads();                               // vmcnt(0) drain inserted here
        #pragma unroll
        for (int ks = 0; ks < 2; ++ks) {
            s16x8 a[2], b[4];
            #pragma unroll
            for (int mf = 0; mf < 2; ++mf) {
                int r = wm + mf * 16 + fm;
                a[mf] = *(const s16x8*)&Asl[(r << 6) + ((((ks << 2) + q) ^ (r & 7)) << 3)];
            }
            #pragma unroll
            for (int nf = 0; nf < 4; ++nf) {
                int r = wn + nf * 16 + fm;
                b[nf] = *(const s16x8*)&Bsl[(r << 6) + ((((ks << 2) + q) ^ (r & 7)) << 3)];
            }
            #pragma unroll
            for (int mf = 0; mf < 2; ++mf)
                #pragma unroll
                for (int nf = 0; nf < 4; ++nf)
                    acc[mf][nf] = __builtin_amdgcn_mfma_f32_16x16x32_bf16(a[mf], b[nf], acc[mf][nf], 0, 0, 0);
        }
        __syncthreads();
    }

    if (partial) {                                     // deterministic per-split panel
        float* Cs = C + (size_t)blockIdx.z * ((size_t)M * N);
        #pragma unroll
        for (int mf = 0; mf < 2; ++mf)
            #pragma unroll
            for (int nf = 0; nf < 4; ++nf)
                #pragma unroll
                for (int r = 0; r < 4; ++r) {
                    int m = m0 + wm + mf * 16 + q * 4 + r;
                    int n = n0 + wn + nf * 16 + fm;
                    Cs[(size_t)m * N + n] = acc[mf][nf][r];
                }
    } else {                                           // fallback: atomic accumulate
        #pragma unroll
        for (int mf = 0; mf < 2; ++mf)
            #pragma unroll
            for (int nf = 0; nf < 4; ++nf)
                #pragma unroll
                for (int r = 0; r < 4; ++r) {
                    int m = m0 + wm + mf * 16 + q * 4 + r;
                    int n = n0 + wn + nf * 16 + fm;
                    atomicAdd(&C[(size_t)m * N + n], acc[mf][nf][r]);
                }
    }
}

// ---------- gemm2: 64x64xBK64, global_load_lds + XOR-swizzle, + bias, fused PAPR loss ----------
__global__ __launch_bounds__(256) void gemm2_k(const ushort* __restrict__ Ab,
        const ushort* __restrict__ Bb, const float* __restrict__ bias,
        const float* __restrict__ papr, float* __restrict__ C,
        float* __restrict__ out_loss, int M, int N, int K)
{
    __shared__ __attribute__((aligned(16))) ushort Asl[64 * 64];
    __shared__ __attribute__((aligned(16))) ushort Bsl[64 * 64];
    __shared__ float red[4];
    const int tid = threadIdx.x;
    const int lane = tid & 63, wave = tid >> 6;
    const int wm = (wave >> 1) * 32, wn = (wave & 1) * 32;
    const int m0 = blockIdx.y * 64, n0 = blockIdx.x * 64;
    const int fm = lane & 15, q = lane >> 4;
    f32x4 acc[2][2] = {};

    int srow[2], skb[2];
    #pragma unroll
    for (int j = 0; j < 2; ++j) {
        int c = ((wave * 2 + j) << 6) + lane;
        srow[j] = c >> 3; skb[j] = (c & 7) ^ (srow[j] & 7);
    }

    for (int kt = 0; kt < K; kt += 64) {
        #pragma unroll
        for (int j = 0; j < 2; ++j) {
            gl_lds16(&Ab[(size_t)(m0 + srow[j]) * K + kt + skb[j] * 8],
                     &Asl[(wave * 2 + j) << 9]);
            gl_lds16(&Bb[(size_t)(n0 + srow[j]) * K + kt + skb[j] * 8],
                     &Bsl[(wave * 2 + j) << 9]);
        }
        __syncthreads();
        #pragma unroll
        for (int ks = 0; ks < 2; ++ks) {
            s16x8 a[2], b[2];
            #pragma unroll
            for (int mf = 0; mf < 2; ++mf) {
                int r = wm + mf * 16 + fm;
                a[mf] = *(const s16x8*)&Asl[(r << 6) + ((((ks << 2) + q) ^ (r & 7)) << 3)];
            }
            #pragma unroll
            for (int nf = 0; nf < 2; ++nf) {
                int r = wn + nf * 16 + fm;
                b[nf] = *(const s16x8*)&Bsl[(r << 6) + ((((ks << 2) + q) ^ (r & 7)) << 3)];
            }
            #pragma unroll
            for (int mf = 0; mf < 2; ++mf)
                #pragma unroll
                for (int nf = 0; nf < 2; ++nf)
                    acc[mf][nf] = __builtin_amdgcn_mfma_f32_16x16x32_bf16(a[mf], b[nf], acc[mf][nf], 0, 0, 0);
        }
        __syncthreads();
    }

    #pragma unroll
    for (int mf = 0; mf < 2; ++mf)
        #pragma unroll
        for (int nf = 0; nf < 2; ++nf)
            #pragma unroll
            for (int r = 0; r < 4; ++r) {
                int m = m0 + wm + mf * 16 + q * 4 + r;
                int n = n0 + wn + nf * 16 + fm;
                C[(size_t)m * N + n] = acc[mf][nf][r] + bias[n];
            }

    if (blockIdx.x == 0 && blockIdx.y == 0) {          // fused PAPR loss
        float s = 0.f;
        for (int i = tid; i < 1024; i += 256) { float v = papr[i] - 8.f; s += v > 0.f ? v : 0.f; }
        s = wave_sum(s);
        if (lane == 0) red[wave] = s;
        __syncthreads();
        if (tid == 0) *out_loss = (red[0] + red[1] + red[2] + red[3]) * (1.f / 1024.f);
    }
}

// ---------- megakernel: 2 batch rows / block, shared twiddle+tap reads (LDS-issue diet) ----------
__global__ __launch_bounds__(512, 4) void mega_k(const float* __restrict__ z,
        const float* __restrict__ benc,
        const float* __restrict__ rrc, const float* __restrict__ awgn,
        const int* __restrict__ slocp, ushort* __restrict__ y5b,
        float* __restrict__ papr, float* __restrict__ out_papr, int nsp)
{
    __shared__ float  zl[2][512];
    __shared__ float2 frfi[2][8][32];
    __shared__ float2 trti[2][672];    // per row: [0..15]=0 | data [16..655] | pads; reused as dp/dm after P6
    __shared__ float  hl[132];
    __shared__ float  csl[16], ssl[16];
    __shared__ float2 cs64[64];
    __shared__ __attribute__((aligned(16))) float2 gcs[130];
    __shared__ float  dxr[2][SWZ(L1_ - 1) + 1];
    __shared__ float  red[2][8], red2[2][8];

    const int b0 = blockIdx.x * 2, b1 = b0 + 1;
    const int tid = threadIdx.x;
    const int lane = tid & 63, wv = tid >> 6;
    const int sloc = *slocp;

    // ---- tables ----
    if (tid < 64) {
        float ang = 0.09817477042468103f * (float)tid;   // 2pi/64
        float s, c; sincosf(ang, &s, &c);
        cs64[tid] = make_float2(c, s);
    }
    if (tid >= 64 && tid < 80) {
        int t = tid - 64;
        float ang = 1.9634954084936207f * (float)t;      // 2pi*5/16
        float s, c; sincosf(ang, &s, &c);
        csl[t] = 1.4142135623730951f * c; ssl[t] = 1.4142135623730951f * s;
    }
    if (tid >= 96 && tid < 160) {                        // trti zero pads, both rows
        int t = (tid - 96) & 31, row = (tid - 96) >> 5;
        int idx = (t < 16) ? t : (640 + t);              // [0..15] and [656..671]
        trti[row][idx] = make_float2(0.f, 0.f);
    }
    if (tid >= 256 && tid < 256 + LENRRC_) hl[tid - 256] = rrc[tid - 256];

    // ---- z rows: bias + sum of split-K partial panels (or prereduced fallback) ----
    float va, vb;
    if (nsp) {
        va = benc[tid]; vb = va;
        const float* zp0 = z + (size_t)b0 * 512;
        const float* zp1 = z + (size_t)b1 * 512;
        for (int s = 0; s < nsp; ++s) {
            va += zp0[(size_t)s * 524288 + tid];
            vb += zp1[(size_t)s * 524288 + tid];
        }
    } else {
        va = z[(size_t)b0 * 512 + tid];
        vb = z[(size_t)b1 * 512 + tid];
    }
    __syncthreads();

    // ---- gcs: carrier folded into RRC taps ----
    if (tid < LENRRC_) {
        int neg = (16 - (tid & 15)) & 15;                // (-d) & 15
        gcs[tid] = make_float2(hl[tid] * csl[neg], hl[tid] * ssl[neg]);
    }

    // ---- power norm (single pass: S, Q; ddof=1), both rows ----
    {
        float S0 = wave_sum(va), Q0 = wave_sum(va * va);
        float S1 = wave_sum(vb), Q1 = wave_sum(vb * vb);
        if (lane == 0) { red[0][wv] = S0; red2[0][wv] = Q0; red[1][wv] = S1; red2[1][wv] = Q1; }
    }
    __syncthreads();
    {
        float S0 = 0.f, Q0 = 0.f, S1 = 0.f, Q1 = 0.f;
        #pragma unroll
        for (int w = 0; w < 8; ++w) {
            S0 += red[0][w]; Q0 += red2[0][w];
            S1 += red[1][w]; Q1 += red2[1][w];
        }
        float m0 = S0 * (1.f / 512.f), m1 = S1 * (1.f / 512.f);
        float i0 = 1.f / (sqrtf((Q0 - S0 * m0) * (1.f / 511.f)) + 1e-8f);
        float i1 = 1.f / (sqrtf((Q1 - S1 * m1) * (1.f / 511.f)) + 1e-8f);
        zl[0][tid] = (va - m0) * i0;
        zl[1][tid] = (vb - m1) * i1;
    }
    __syncthreads();

    // ---- P1: DFT32 (+fftshift folded), 256 active, both rows share twiddles ----
    if (tid < 256) {
        int s = tid >> 5, kk = tid & 31;
        int kk2 = (kk + 16) & 31;
        float sr0 = 0.f, si0 = 0.f, sr1 = 0.f, si1 = 0.f;
        int t2 = 0;
        #pragma unroll 4
        for (int q = 0; q < 32; ++q) {
            float2 w = cs64[2 * t2];
            float2 c0 = *(const float2*)&zl[0][(s * 32 + q) * 2];
            float2 c1 = *(const float2*)&zl[1][(s * 32 + q) * 2];
            sr0 += c0.x * w.x + c0.y * w.y;              // * e^{-i ang}
            si0 += c0.y * w.x - c0.x * w.y;
            sr1 += c1.x * w.x + c1.y * w.y;
            si1 += c1.y * w.x - c1.x * w.y;
            t2 = (t2 + kk2) & 31;
        }
        const float sc = 0.1767766952966369f;
        frfi[0][s][kk] = make_float2(sr0 * sc, si0 * sc);
        frfi[1][s][kk] = make_float2(sr1 * sc, si1 * sc);
    }
    __syncthreads();

    // ---- P2: IDFT64 + CP, n/(n+32) fold, 256 active, shared twiddles ----
    if (tid < 256) {
        int s = tid >> 5, n = tid & 31;                  // each -> pair (n, n+32)
        float er0 = 0.f, ei0 = 0.f, o_r0 = 0.f, o_i0 = 0.f;
        float er1 = 0.f, ei1 = 0.f, o_r1 = 0.f, o_i1 = 0.f;
        int t = (sloc * n) & 63;
        #pragma unroll 2
        for (int k = 0; k < 32; k += 2) {
            float2 w = cs64[t];
            float2 f0 = frfi[0][s][k], f1 = frfi[1][s][k];
            er0 += f0.x * w.x - f0.y * w.y;              // * e^{+i ang}
            ei0 += f0.y * w.x + f0.x * w.y;
            er1 += f1.x * w.x - f1.y * w.y;
            ei1 += f1.y * w.x + f1.x * w.y;
            t = (t + n) & 63;
            w = cs64[t];
            f0 = frfi[0][s][k + 1]; f1 = frfi[1][s][k + 1];
            o_r0 += f0.x * w.x - f0.y * w.y;
            o_i0 += f0.y * w.x + f0.x * w.y;
            o_r1 += f1.x * w.x - f1.y * w.y;
            o_i1 += f1.y * w.x + f1.x * w.y;
            t = (t + n) & 63;
        }
        float sgn = (sloc & 1) ? -1.f : 1.f;
        int base = s * 80;                               // data at [base+32 .. base+95]
        {
            float dr0 = (er0 + o_r0) * 0.125f, di0 = (ei0 + o_i0) * 0.125f;
            float dr1 = sgn * (er0 - o_r0) * 0.125f, di1 = sgn * (ei0 - o_i0) * 0.125f;
            trti[0][base + 32 + n] = make_float2(dr0, di0);
            trti[0][base + 64 + n] = make_float2(dr1, di1);
            if (n >= 16) trti[0][base + n] = make_float2(dr1, di1);   // CP
        }
        {
            float dr0 = (er1 + o_r1) * 0.125f, di0 = (ei1 + o_i1) * 0.125f;
            float dr1 = sgn * (er1 - o_r1) * 0.125f, di1 = sgn * (ei1 - o_i1) * 0.125f;
            trti[1][base + 32 + n] = make_float2(dr0, di0);
            trti[1][base + 64 + n] = make_float2(dr1, di1);
            if (n >= 16) trti[1][base + n] = make_float2(dr1, di1);   // CP
        }
    }
    __syncthreads();

    // ---- P3: upsample x8 + RRC polyphase + carrier, task=(a,g), both rows share hl ----
    float ss0 = 0.f, ss1 = 0.f;
    for (int tsk = tid; tsk < 1312; tsk += 512) {
        int a = tsk >> 1, g = tsk & 1;
        float ar0[4] = {}, ai0[4] = {}, ar1[4] = {}, ai1[4] = {};
        #pragma unroll 4
        for (int d = 0; d < 16; ++d) {
            float2 t0 = trti[0][16 + a - d];             // zero-padded: no bounds check
            float2 t1 = trti[1][16 + a - d];
            #pragma unroll
            for (int r = 0; r < 4; ++r) {
                float h = hl[g * 4 + r + 8 * d];
                ar0[r] += t0.x * h; ai0[r] += t0.y * h;
                ar1[r] += t1.x * h; ai1[r] += t1.y * h;
            }
        }
        if (g == 0) {                                    // d=16, tap 128, r=0 only
            float2 t0 = trti[0][a], t1 = trti[1][a];
            float h = hl[128];
            ar0[0] += t0.x * h; ai0[0] += t0.y * h;
            ar1[0] += t1.x * h; ai1[0] += t1.y * h;
        }
        int cb = (a & 1) * 8;
        #pragma unroll
        for (int r = 0; r < 4; ++r) {
            int rr = g * 4 + r;
            float cv = csl[cb + rr], sv = ssl[cb + rr];
            float v0 = ar0[r] * cv - ai0[r] * sv;
            float v1 = ar1[r] * cv - ai1[r] * sv;
            dxr[0][SWZ(a * 8 + rr)] = v0;
            dxr[1][SWZ(a * 8 + rr)] = v1;
            ss0 += v0 * v0; ss1 += v1 * v1;
        }
    }
    ss0 = wave_sum(ss0); ss1 = wave_sum(ss1);
    if (lane == 0) { red[0][wv] = ss0; red[1][wv] = ss1; }
    __syncthreads();
    float thr0, thr1;
    {
        float S0 = 0.f, S1 = 0.f;
        #pragma unroll
        for (int w = 0; w < 8; ++w) { S0 += red[0][w]; S1 += red[1][w]; }
        thr0 = 1.2f * sqrtf(S0 / (float)L1_);
        thr1 = 1.2f * sqrtf(S1 / (float)L1_);
    }
    __syncthreads();

    // ---- P5: clip + PAPR window stats + AWGN (in place), both rows ----
    float pm0 = 0.f, ps0 = 0.f, pm1 = 0.f, ps1 = 0.f;
    {
        const float4* ag0 = (const float4*)&awgn[(size_t)b0 * L1_];
        const float4* ag1 = (const float4*)&awgn[(size_t)b1 * L1_];
        for (int ii = tid; ii < 1312; ii += 512) {       // 1312*4 = 5248
            float4 a0 = ag0[ii], a1 = ag1[ii];
            int i = ii * 4;
            #pragma unroll
            for (int e = 0; e < 4; ++e) {
                int idx = i + e;
                bool win = (idx >= TSTART_ && idx < TSTART_ + NWIN_);
                float aw0 = (e == 0) ? a0.x : (e == 1) ? a0.y : (e == 2) ? a0.z : a0.w;
                float aw1 = (e == 0) ? a1.x : (e == 1) ? a1.y : (e == 2) ? a1.z : a1.w;
                {
                    float x = dxr[0][SWZ(idx)];
                    float ax = fabsf(x);
                    float over = fmaxf(ax - thr0, 0.f);
                    float y = (1.f - over / (ax + 1e-8f)) * x;
                    if (win) { float p = y * y; ps0 += p; pm0 = fmaxf(pm0, p); }
                    dxr[0][SWZ(idx)] = y + aw0;
                }
                {
                    float x = dxr[1][SWZ(idx)];
                    float ax = fabsf(x);
                    float over = fmaxf(ax - thr1, 0.f);
                    float y = (1.f - over / (ax + 1e-8f)) * x;
                    if (win) { float p = y * y; ps1 += p; pm1 = fmaxf(pm1, p); }
                    dxr[1][SWZ(idx)] = y + aw1;
                }
            }
        }
    }
    ps0 = wave_sum(ps0); pm0 = wave_max(pm0);
    ps1 = wave_sum(ps1); pm1 = wave_max(pm1);
    if (lane == 0) { red[0][wv] = ps0; red2[0][wv] = pm0; red[1][wv] = ps1; red2[1][wv] = pm1; }
    __syncthreads();
    if (tid == 0) {
        float s0 = 0.f, m0 = 0.f, s1 = 0.f, m1 = 0.f;
        #pragma unroll
        for (int w = 0; w < 8; ++w) {
            s0 += red[0][w]; m0 = fmaxf(m0, red2[0][w]);
            s1 += red[1][w]; m1 = fmaxf(m1, red2[1][w]);
        }
        float p0 = 10.f * log10f(m0 / (s0 / (float)NWIN_));
        float p1 = 10.f * log10f(m1 / (s1 / (float)NWIN_));
        papr[b0] = p0; out_papr[b0] = p0;
        papr[b1] = p1; out_papr[b1] = p1;
    }
    __syncthreads();     // all P5 dxr writes visible before P6

    // ---- P6: matched RRC filter, shared float4 gcs reads + in-wave +/- fold ----
    {
        int s = wv, n = lane;                            // 8 waves x 64 outputs, both rows
        int T0 = s * 80 + n + 32;                        // Nf/8
        int base = 9 * T0;                               // SWZ(Nf)
        float ar0 = 0.f, ai0 = 0.f, ar1 = 0.f, ai1 = 0.f;
        int db = 0;
        #pragma unroll 4
        for (int e = 0; e < 16; ++e) {
            float4 g01 = *(const float4*)&gcs[db];       // gcs[db], gcs[db+1]
            float4 g23 = *(const float4*)&gcs[db + 2];
            float4 g45 = *(const float4*)&gcs[db + 4];
            float4 g67 = *(const float4*)&gcs[db + 6];
            float gx[8] = { g01.x, g01.z, g23.x, g23.z, g45.x, g45.z, g67.x, g67.z };
            float gy[8] = { g01.y, g01.w, g23.y, g23.w, g45.y, g45.w, g67.y, g67.w };
            #pragma unroll
            for (int u = 0; u < 8; ++u) {
                int off = (u == 0) ? 0 : (u + 1);
                float v0 = dxr[0][base - off];
                float v1 = dxr[1][base - off];
                ar0 += v0 * gx[u]; ai0 += v0 * gy[u];
                ar1 += v1 * gx[u]; ai1 += v1 * gy[u];
            }
            base -= 9; db += 8;
        }
        {
            float2 g = gcs[128];
            float v0 = dxr[0][base], v1 = dxr[1][base];
            ar0 += v0 * g.x; ai0 += v0 * g.y;
            ar1 += v1 * g.x; ai1 += v1 * g.y;
        }
        bool odd = (n & 1);
        float dx0 = odd ? -ar0 : ar0, dy0 = odd ? ai0 : -ai0;
        float dx1 = odd ? -ar1 : ar1, dy1 = odd ? ai1 : -ai1;
        float px0 = __shfl_xor(dx0, 32, 64), py0 = __shfl_xor(dy0, 32, 64);
        float px1 = __shfl_xor(dx1, 32, 64), py1 = __shfl_xor(dy1, 32, 64);
        // lanes 0..31: dp = d[n]+d[n+32]; lanes 32..63: dm = d[n-32]-d[n]
        float2 r0 = (n < 32) ? make_float2(dx0 + px0, dy0 + py0)
                             : make_float2(px0 - dx0, py0 - dy0);
        float2 r1 = (n < 32) ? make_float2(dx1 + px1, dy1 + py1)
                             : make_float2(px1 - dx1, py1 - dy1);
        int di = ((n >> 5) * 256) + s * 32 + (n & 31);
        trti[0][di] = r0;
        trti[1][di] = r1;
    }
    __syncthreads();

    // ---- P7: DFT64 -> band select -> fftshift, n-fold, 256 active, shared twiddles ----
    if (tid < 256) {
        int s = tid >> 5, kk = tid & 31;
        int f = sloc + kk;
        int doff = ((f & 1) ? 256 : 0) + s * 32;
        const float2* d0 = &trti[0][doff];
        const float2* d1 = &trti[1][doff];
        float vr0 = 0.f, vi0 = 0.f, vr1 = 0.f, vi1 = 0.f;
        int t = 0;
        #pragma unroll 4
        for (int n = 0; n < 32; ++n) {
            float2 w = cs64[t];
            float2 e0 = d0[n], e1 = d1[n];
            vr0 += e0.x * w.x + e0.y * w.y;              // * e^{-i ang}
            vi0 += e0.y * w.x - e0.x * w.y;
            vr1 += e1.x * w.x + e1.y * w.y;
            vi1 += e1.y * w.x - e1.x * w.y;
            t = (t + f) & 63;
        }
        int ksh = (kk + 16) & 31;
        frfi[0][s][ksh] = make_float2(vr0 * 0.125f, vi0 * 0.125f);
        frfi[1][s][ksh] = make_float2(vr1 * 0.125f, vi1 * 0.125f);
    }
    __syncthreads();

    // ---- P8: IDFT32 -> y5 single bf16 plane, 256 active, shared twiddles ----
    if (tid < 256) {
        int s = tid >> 5, q2 = tid & 31;
        float ur0 = 0.f, ui0 = 0.f, ur1 = 0.f, ui1 = 0.f;
        int t2 = 0;
        #pragma unroll 4
        for (int k = 0; k < 32; ++k) {
            float2 w = cs64[2 * t2];
            float2 f0 = frfi[0][s][k], f1 = frfi[1][s][k];
            ur0 += f0.x * w.x - f0.y * w.y;              // * e^{+i ang}
            ui0 += f0.y * w.x + f0.x * w.y;
            ur1 += f1.x * w.x - f1.y * w.y;
            ui1 += f1.y * w.x + f1.x * w.y;
            t2 = (t2 + q2) & 31;
        }
        const float sc = 0.1767766952966369f;
        ushort2 h0; h0.x = bf16_rne(ur0 * sc); h0.y = bf16_rne(ui0 * sc);
        ushort2 h1; h1.x = bf16_rne(ur1 * sc); h1.y = bf16_rne(ui1 * sc);
        *(ushort2*)&y5b[(size_t)b0 * 512 + (s * 32 + q2) * 2] = h0;
        *(ushort2*)&y5b[(size_t)b1 * 512 + (s * 32 + q2) * 2] = h1;
    }
}

extern "C" void kernel_launch(void* const* d_in, const int* in_sizes, int n_in,
                              void* d_out, int out_size, void* d_ws, size_t ws_size,
                              hipStream_t stream) {
    const float* x    = (const float*)d_in[0];
    const float* Wenc = (const float*)d_in[1];
    const float* benc = (const float*)d_in[2];
    const float* Wdec = (const float*)d_in[3];
    const float* bdec = (const float*)d_in[4];
    const float* rrc  = (const float*)d_in[5];
    const float* awgn = (const float*)d_in[6];
    const int* sloc   = (const int*)d_in[7];
    float* out = (float*)d_out;

    char* wsb = (char*)d_ws;
    ushort* xb   = (ushort*)wsb;                     wsb += (size_t)1024 * 3072 * 2;
    ushort* w1t  = (ushort*)wsb;                     wsb += (size_t)512 * 3072 * 2;
    ushort* w2t  = (ushort*)wsb;                     wsb += (size_t)3072 * 512 * 2;
    ushort* y5b  = (ushort*)wsb;                     wsb += (size_t)1024 * 512 * 2;
    float*  papr = (float*)wsb;                      wsb += 1024 * 4;
    float*  zbuf = (float*)wsb;                      // partial: 8 x 1024x512 f32 (16.8 MB)
                                                     // fallback: 1024x512 f32 (2.1 MB)
    size_t head = (size_t)((char*)zbuf - (char*)d_ws);
    int partial = (ws_size >= head + (size_t)8 * 1024 * 512 * 4) ? 1 : 0;

    float* out_papr = out + (size_t)1024 * 3072;
    float* out_loss = out_papr + 1024;

    pack_k<<<partial ? 3840 : 5888, 256, 0, stream>>>(x, Wenc, Wdec, benc, xb, w1t, w2t, zbuf);
    gemm1_k<<<dim3(4, 16, 8), 256, 0, stream>>>(xb, w1t, zbuf, 1024, 512, 3072, partial);
    mega_k<<<512, 512, 0, stream>>>(zbuf, benc, rrc, awgn, sloc, y5b, papr, out_papr,
                                    partial ? 8 : 0);
    gemm2_k<<<dim3(48, 16, 1), 256, 0, stream>>>(y5b, w2t, bdec, papr, out, out_loss, 1024, 3072, 512);
}

// Round 6
// 145.455 us; speedup vs baseline: 1.0779x; 1.0157x over previous
//
#include <hip/hip_runtime.h>
#include <hip/hip_bf16.h>
#include <math.h>

#define L1_     5248
#define LENRRC_ 129
#define TSTART_ 65
#define NWIN_   5120
#define SWZ(m) ((m) + ((m) >> 3))     // stride-8 reads -> stride-9 -> conflict-free

typedef __attribute__((ext_vector_type(8))) short s16x8;   // 8 bf16 lanes (4 VGPRs)
typedef __attribute__((ext_vector_type(4))) float f32x4;   // MFMA accumulator

__device__ inline ushort bf16_rne(float x) {
    unsigned xb = __float_as_uint(x);
    return (ushort)((xb + 0x7fffu + ((xb >> 16) & 1u)) >> 16);
}

__device__ inline float wave_sum(float v) {
    #pragma unroll
    for (int m = 32; m > 0; m >>= 1) v += __shfl_xor(v, m, 64);
    return v;
}
__device__ inline float wave_max(float v) {
    #pragma unroll
    for (int m = 32; m > 0; m >>= 1) v = fmaxf(v, __shfl_xor(v, m, 64));
    return v;
}

// direct global->LDS 16B staging (dest = wave-uniform base + lane*16)
__device__ inline void gl_lds16(const void* g, void* l) {
    __builtin_amdgcn_global_load_lds(
        (const __attribute__((address_space(1))) unsigned int*)g,
        (__attribute__((address_space(3))) unsigned int*)l, 16, 0, 0);
}

// ---------- pack: W1^T bf16 | W2^T bf16 | (fallback: z=bias) ----------
__global__ __launch_bounds__(256) void pack_k(const float* __restrict__ W1,
        const float* __restrict__ W2, const float* __restrict__ benc,
        ushort* __restrict__ w1t, ushort* __restrict__ w2t, float* __restrict__ z)
{
    __shared__ ushort tile[64][70];
    const int blk = blockIdx.x, tid = threadIdx.x;
    if (blk < 768) {                                   // transpose W1 / W2 into bf16
        const float* W; ushort* T; int K, N, n0, k0;
        if (blk < 384) {
            int idx = blk;                             // grid (8,48)
            W = W1; T = w1t; K = 3072; N = 512;
            n0 = (idx & 7) * 64; k0 = (idx >> 3) * 64;
        } else {
            int idx = blk - 384;                       // grid (48,8)
            W = W2; T = w2t; K = 512; N = 3072;
            n0 = (idx % 48) * 64; k0 = (idx / 48) * 64;
        }
        const int cr = tid >> 4, cc = (tid & 15) * 4;
        #pragma unroll
        for (int i = 0; i < 4; ++i) {
            int kk = i * 16 + cr;
            float4 v = *(const float4*)&W[(size_t)(k0 + kk) * N + n0 + cc];
            tile[kk][cc]     = bf16_rne(v.x);
            tile[kk][cc + 1] = bf16_rne(v.y);
            tile[kk][cc + 2] = bf16_rne(v.z);
            tile[kk][cc + 3] = bf16_rne(v.w);
        }
        __syncthreads();
        #pragma unroll
        for (int i = 0; i < 4; ++i) {
            int nn = i * 16 + cr;
            ushort4 h;
            h.x = tile[cc][nn]; h.y = tile[cc + 1][nn];
            h.z = tile[cc + 2][nn]; h.w = tile[cc + 3][nn];
            *(ushort4*)&T[(size_t)(n0 + nn) * K + k0 + cc] = h;
        }
    } else {                                           // fallback only: init z with bias
        int i = (blk - 768) * 256 + tid;               // 524288 total
        z[i] = benc[i & 511];
    }
}

// ---------- gemm1: A from f32 x (cvt in-flight), B gl_lds, SK=8 partial panels ----------
__global__ __launch_bounds__(256) void gemm1_k(const float* __restrict__ Ax,
        const ushort* __restrict__ Bb, float* __restrict__ C, int M, int N, int K,
        int partial)
{
    __shared__ __attribute__((aligned(16))) ushort Asl[64 * 64];    // 8 KB, linear
    __shared__ __attribute__((aligned(16))) ushort Bsl[128 * 64];   // 16 KB, linear
    const int tid = threadIdx.x;
    const int lane = tid & 63, wave = tid >> 6;
    const int wm = (wave >> 1) * 32, wn = (wave & 1) * 64;
    const int m0 = blockIdx.y * 64, n0 = blockIdx.x * 128;
    const int kch = K / 8, kbeg = blockIdx.z * kch, kend = kbeg + kch;
    const int fm = lane & 15, q = lane >> 4;
    f32x4 acc[2][4] = {};

    // per-lane staging coords: chunk c -> (row, kb) with kb inverse-swizzled,
    // so linear LDS dest holds the XOR-swizzled layout (rule 21: both-sides)
    int arow[2], akb[2], brow[4], bkb[4];
    #pragma unroll
    for (int j = 0; j < 2; ++j) {
        int c = ((wave * 2 + j) << 6) + lane;
        arow[j] = c >> 3; akb[j] = (c & 7) ^ (arow[j] & 7);
    }
    #pragma unroll
    for (int j = 0; j < 4; ++j) {
        int c = ((wave * 4 + j) << 6) + lane;
        brow[j] = c >> 3; bkb[j] = (c & 7) ^ (brow[j] & 7);
    }

    for (int kt = kbeg; kt < kend; kt += 64) {
        #pragma unroll
        for (int j = 0; j < 4; ++j)                    // B 128x64: DMA first (overlaps A cvt)
            gl_lds16(&Bb[(size_t)(n0 + brow[j]) * K + kt + bkb[j] * 8],
                     &Bsl[(wave * 4 + j) << 9]);
        #pragma unroll
        for (int j = 0; j < 2; ++j) {                  // A 64x64: f32 load -> bf16 -> ds_write
            int c = ((wave * 2 + j) << 6) + lane;
            const float* src = &Ax[(size_t)(m0 + arow[j]) * K + kt + akb[j] * 8];
            float4 v0 = *(const float4*)src;
            float4 v1 = *(const float4*)(src + 4);
            s16x8 hv;
            hv[0] = (short)bf16_rne(v0.x); hv[1] = (short)bf16_rne(v0.y);
            hv[2] = (short)bf16_rne(v0.z); hv[3] = (short)bf16_rne(v0.w);
            hv[4] = (short)bf16_rne(v1.x); hv[5] = (short)bf16_rne(v1.y);
            hv[6] = (short)bf16_rne(v1.z); hv[7] = (short)bf16_rne(v1.w);
            *(s16x8*)&Asl[c * 8] = hv;
        }
        __syncthreads();                               // vmcnt+lgkm drain inserted here
        #pragma unroll
        for (int ks = 0; ks < 2; ++ks) {
            s16x8 a[2], b[4];
            #pragma unroll
            for (int mf = 0; mf < 2; ++mf) {
                int r = wm + mf * 16 + fm;
                a[mf] = *(const s16x8*)&Asl[(r << 6) + ((((ks << 2) + q) ^ (r & 7)) << 3)];
            }
            #pragma unroll
            for (int nf = 0; nf < 4; ++nf) {
                int r = wn + nf * 16 + fm;
                b[nf] = *(const s16x8*)&Bsl[(r << 6) + ((((ks << 2) + q) ^ (r & 7)) << 3)];
            }
            #pragma unroll
            for (int mf = 0; mf < 2; ++mf)
                #pragma unroll
                for (int nf = 0; nf < 4; ++nf)
                    acc[mf][nf] = __builtin_amdgcn_mfma_f32_16x16x32_bf16(a[mf], b[nf], acc[mf][nf], 0, 0, 0);
        }
        __syncthreads();
    }

    if (partial) {                                     // deterministic per-split panel
        float* Cs = C + (size_t)blockIdx.z * ((size_t)M * N);
        #pragma unroll
        for (int mf = 0; mf < 2; ++mf)
            #pragma unroll
            for (int nf = 0; nf < 4; ++nf)
                #pragma unroll
                for (int r = 0; r < 4; ++r) {
                    int m = m0 + wm + mf * 16 + q * 4 + r;
                    int n = n0 + wn + nf * 16 + fm;
                    Cs[(size_t)m * N + n] = acc[mf][nf][r];
                }
    } else {                                           // fallback: atomic accumulate
        #pragma unroll
        for (int mf = 0; mf < 2; ++mf)
            #pragma unroll
            for (int nf = 0; nf < 4; ++nf)
                #pragma unroll
                for (int r = 0; r < 4; ++r) {
                    int m = m0 + wm + mf * 16 + q * 4 + r;
                    int n = n0 + wn + nf * 16 + fm;
                    atomicAdd(&C[(size_t)m * N + n], acc[mf][nf][r]);
                }
    }
}

// ---------- gemm2: 64x64xBK64, global_load_lds + XOR-swizzle, + bias, fused PAPR loss ----------
__global__ __launch_bounds__(256) void gemm2_k(const ushort* __restrict__ Ab,
        const ushort* __restrict__ Bb, const float* __restrict__ bias,
        const float* __restrict__ papr, float* __restrict__ C,
        float* __restrict__ out_loss, int M, int N, int K)
{
    __shared__ __attribute__((aligned(16))) ushort Asl[64 * 64];
    __shared__ __attribute__((aligned(16))) ushort Bsl[64 * 64];
    __shared__ float red[4];
    const int tid = threadIdx.x;
    const int lane = tid & 63, wave = tid >> 6;
    const int wm = (wave >> 1) * 32, wn = (wave & 1) * 32;
    const int m0 = blockIdx.y * 64, n0 = blockIdx.x * 64;
    const int fm = lane & 15, q = lane >> 4;
    f32x4 acc[2][2] = {};

    int srow[2], skb[2];
    #pragma unroll
    for (int j = 0; j < 2; ++j) {
        int c = ((wave * 2 + j) << 6) + lane;
        srow[j] = c >> 3; skb[j] = (c & 7) ^ (srow[j] & 7);
    }

    for (int kt = 0; kt < K; kt += 64) {
        #pragma unroll
        for (int j = 0; j < 2; ++j) {
            gl_lds16(&Ab[(size_t)(m0 + srow[j]) * K + kt + skb[j] * 8],
                     &Asl[(wave * 2 + j) << 9]);
            gl_lds16(&Bb[(size_t)(n0 + srow[j]) * K + kt + skb[j] * 8],
                     &Bsl[(wave * 2 + j) << 9]);
        }
        __syncthreads();
        #pragma unroll
        for (int ks = 0; ks < 2; ++ks) {
            s16x8 a[2], b[2];
            #pragma unroll
            for (int mf = 0; mf < 2; ++mf) {
                int r = wm + mf * 16 + fm;
                a[mf] = *(const s16x8*)&Asl[(r << 6) + ((((ks << 2) + q) ^ (r & 7)) << 3)];
            }
            #pragma unroll
            for (int nf = 0; nf < 2; ++nf) {
                int r = wn + nf * 16 + fm;
                b[nf] = *(const s16x8*)&Bsl[(r << 6) + ((((ks << 2) + q) ^ (r & 7)) << 3)];
            }
            #pragma unroll
            for (int mf = 0; mf < 2; ++mf)
                #pragma unroll
                for (int nf = 0; nf < 2; ++nf)
                    acc[mf][nf] = __builtin_amdgcn_mfma_f32_16x16x32_bf16(a[mf], b[nf], acc[mf][nf], 0, 0, 0);
        }
        __syncthreads();
    }

    #pragma unroll
    for (int mf = 0; mf < 2; ++mf)
        #pragma unroll
        for (int nf = 0; nf < 2; ++nf)
            #pragma unroll
            for (int r = 0; r < 4; ++r) {
                int m = m0 + wm + mf * 16 + q * 4 + r;
                int n = n0 + wn + nf * 16 + fm;
                C[(size_t)m * N + n] = acc[mf][nf][r] + bias[n];
            }

    if (blockIdx.x == 0 && blockIdx.y == 0) {          // fused PAPR loss
        float s = 0.f;
        for (int i = tid; i < 1024; i += 256) { float v = papr[i] - 8.f; s += v > 0.f ? v : 0.f; }
        s = wave_sum(s);
        if (lane == 0) red[wave] = s;
        __syncthreads();
        if (tid == 0) *out_loss = (red[0] + red[1] + red[2] + red[3]) * (1.f / 1024.f);
    }
}

// ---------- megakernel: 2 rows/block, collapsed DFTs (P12/P78 via cot identity) ----------
// P1+P2 == IDFT64(fftshift(DFT32(z))): with z~[q]=(-1)^q z[q],
//   d[2m]  = (1/sqrt2) * e^{2pi i 2m sloc/64} * z~[m]                   (interpolation identity)
//   d[odd n] = (1/sqrt2048) * e^{2pi i n sloc/64} * ( Sum z~ + i * Sum z~[q] cot(pi(n-2q)/64) )
// P7+P8 is the adjoint with identical structure on w~[n] = w[n] e^{-2pi i n sloc/64}.
__global__ __launch_bounds__(512, 4) void mega_k(const float* __restrict__ z,
        const float* __restrict__ benc,
        const float* __restrict__ rrc, const float* __restrict__ awgn,
        const int* __restrict__ slocp, ushort* __restrict__ y5b,
        float* __restrict__ papr, float* __restrict__ out_papr, int nsp)
{
    __shared__ float  zl[2][512];
    __shared__ float2 trti[2][672];    // P12 out (CP layout) / reused as w~[s*64+n] after P6
    __shared__ float  hl[132];
    __shared__ float  csl[16], ssl[16];
    __shared__ float2 cs64[64];
    __shared__ float  ct[64];          // cot(pi*j/64), odd j only
    __shared__ __attribute__((aligned(16))) float2 gcs[130];
    __shared__ float  dxr[2][SWZ(L1_ - 1) + 1];
    __shared__ float  red[2][8], red2[2][8];

    const int b0 = blockIdx.x * 2, b1 = b0 + 1;
    const int tid = threadIdx.x;
    const int lane = tid & 63, wv = tid >> 6;
    const int sloc = *slocp;
    const float S2048 = 0.02209708691207961f;            // 1/sqrt(2048)

    // ---- tables ----
    if (tid < 64) {
        float ang = 0.09817477042468103f * (float)tid;   // 2pi/64
        float s, c; sincosf(ang, &s, &c);
        cs64[tid] = make_float2(c, s);
    }
    if (tid >= 64 && tid < 80) {
        int t = tid - 64;
        float ang = 1.9634954084936207f * (float)t;      // 2pi*5/16
        float s, c; sincosf(ang, &s, &c);
        csl[t] = 1.4142135623730951f * c; ssl[t] = 1.4142135623730951f * s;
    }
    if (tid >= 96 && tid < 160) {                        // trti zero pads, both rows
        int t = (tid - 96) & 31, row = (tid - 96) >> 5;
        int idx = (t < 16) ? t : (640 + t);              // [0..15] and [656..671]
        trti[row][idx] = make_float2(0.f, 0.f);
    }
    if (tid >= 160 && tid < 224) {                       // cot table (odd entries)
        int j = tid - 160;
        float v = 0.f;
        if (j & 1) { float s, c; sincosf(0.04908738521234052f * (float)j, &s, &c); v = c / s; }
        ct[j] = v;
    }
    if (tid >= 256 && tid < 256 + LENRRC_) hl[tid - 256] = rrc[tid - 256];

    // ---- z rows: bias + sum of split-K partial panels (or prereduced fallback) ----
    float va, vb;
    if (nsp) {
        va = benc[tid]; vb = va;
        const float* zp0 = z + (size_t)b0 * 512;
        const float* zp1 = z + (size_t)b1 * 512;
        for (int s = 0; s < nsp; ++s) {
            va += zp0[(size_t)s * 524288 + tid];
            vb += zp1[(size_t)s * 524288 + tid];
        }
    } else {
        va = z[(size_t)b0 * 512 + tid];
        vb = z[(size_t)b1 * 512 + tid];
    }
    __syncthreads();

    // ---- gcs: carrier folded into RRC taps ----
    if (tid < LENRRC_) {
        int neg = (16 - (tid & 15)) & 15;                // (-d) & 15
        gcs[tid] = make_float2(hl[tid] * csl[neg], hl[tid] * ssl[neg]);
    }

    // ---- power norm (single pass: S, Q; ddof=1), both rows; fold (-1)^q into zl ----
    {
        float S0 = wave_sum(va), Q0 = wave_sum(va * va);
        float S1 = wave_sum(vb), Q1 = wave_sum(vb * vb);
        if (lane == 0) { red[0][wv] = S0; red2[0][wv] = Q0; red[1][wv] = S1; red2[1][wv] = Q1; }
    }
    __syncthreads();
    {
        float S0 = 0.f, Q0 = 0.f, S1 = 0.f, Q1 = 0.f;
        #pragma unroll
        for (int w = 0; w < 8; ++w) {
            S0 += red[0][w]; Q0 += red2[0][w];
            S1 += red[1][w]; Q1 += red2[1][w];
        }
        float m0 = S0 * (1.f / 512.f), m1 = S1 * (1.f / 512.f);
        float i0 = 1.f / (sqrtf((Q0 - S0 * m0) * (1.f / 511.f)) + 1e-8f);
        float i1 = 1.f / (sqrtf((Q1 - S1 * m1) * (1.f / 511.f)) + 1e-8f);
        float sg = ((tid >> 1) & 1) ? -1.f : 1.f;        // (-1)^q, q = tid>>1
        zl[0][tid] = (va - m0) * i0 * sg;
        zl[1][tid] = (vb - m1) * i1 * sg;
    }
    __syncthreads();

    // ---- P12: fused DFT32+IDFT64+CP. Each thread: 1 odd + 1 even output of its row ----
    {
        int r = tid >> 8, t = tid & 255;
        int s = t >> 5, j = t & 31;
        int base = s * 80;                               // data at [base+32 .. base+95]
        const float2* zs = (const float2*)&zl[r][s * 64];
        // odd n = 2j+1: dense cot sum
        int n = 2 * j + 1;
        float Zr = 0.f, Zi = 0.f, Tr = 0.f, Ti = 0.f;
        #pragma unroll 4
        for (int q = 0; q < 32; ++q) {
            float2 a = zs[q];
            float w = ct[(n - 2 * q) & 63];
            Zr += a.x; Zi += a.y;
            Tr += a.x * w; Ti += a.y * w;
        }
        {
            float2 cw = cs64[(n * sloc) & 63];
            float Ar = Zr - Ti, Ai = Zi + Tr;            // Z + i*T
            float dr = S2048 * (Ar * cw.x - Ai * cw.y);
            float di = S2048 * (Ai * cw.x + Ar * cw.y);
            trti[r][base + 32 + n] = make_float2(dr, di);
            if (n >= 48) trti[r][base + n - 32] = make_float2(dr, di);   // CP
        }
        // even n = 2j: trivial (interpolation identity)
        {
            int n2 = 2 * j;
            float2 a = zs[j];
            float2 cw = cs64[(n2 * sloc) & 63];
            const float RS2 = 0.7071067811865476f;       // 1/sqrt2
            float dr = RS2 * (a.x * cw.x - a.y * cw.y);
            float di = RS2 * (a.y * cw.x + a.x * cw.y);
            trti[r][base + 32 + n2] = make_float2(dr, di);
            if (n2 >= 48) trti[r][base + n2 - 32] = make_float2(dr, di); // CP
        }
    }
    __syncthreads();

    // ---- P3: upsample x8 + RRC polyphase + carrier, task=(a,g), both rows share hl ----
    float ss0 = 0.f, ss1 = 0.f;
    for (int tsk = tid; tsk < 1312; tsk += 512) {
        int a = tsk >> 1, g = tsk & 1;
        float ar0[4] = {}, ai0[4] = {}, ar1[4] = {}, ai1[4] = {};
        #pragma unroll 4
        for (int d = 0; d < 16; ++d) {
            float2 t0 = trti[0][16 + a - d];             // zero-padded: no bounds check
            float2 t1 = trti[1][16 + a - d];
            #pragma unroll
            for (int r = 0; r < 4; ++r) {
                float h = hl[g * 4 + r + 8 * d];
                ar0[r] += t0.x * h; ai0[r] += t0.y * h;
                ar1[r] += t1.x * h; ai1[r] += t1.y * h;
            }
        }
        if (g == 0) {                                    // d=16, tap 128, r=0 only
            float2 t0 = trti[0][a], t1 = trti[1][a];
            float h = hl[128];
            ar0[0] += t0.x * h; ai0[0] += t0.y * h;
            ar1[0] += t1.x * h; ai1[0] += t1.y * h;
        }
        int cb = (a & 1) * 8;
        #pragma unroll
        for (int r = 0; r < 4; ++r) {
            int rr = g * 4 + r;
            float cv = csl[cb + rr], sv = ssl[cb + rr];
            float v0 = ar0[r] * cv - ai0[r] * sv;
            float v1 = ar1[r] * cv - ai1[r] * sv;
            dxr[0][SWZ(a * 8 + rr)] = v0;
            dxr[1][SWZ(a * 8 + rr)] = v1;
            ss0 += v0 * v0; ss1 += v1 * v1;
        }
    }
    ss0 = wave_sum(ss0); ss1 = wave_sum(ss1);
    if (lane == 0) { red[0][wv] = ss0; red[1][wv] = ss1; }
    __syncthreads();
    float thr0, thr1;
    {
        float S0 = 0.f, S1 = 0.f;
        #pragma unroll
        for (int w = 0; w < 8; ++w) { S0 += red[0][w]; S1 += red[1][w]; }
        thr0 = 1.2f * sqrtf(S0 / (float)L1_);
        thr1 = 1.2f * sqrtf(S1 / (float)L1_);
    }
    __syncthreads();

    // ---- P5: clip + PAPR window stats + AWGN (in place), both rows ----
    float pm0 = 0.f, ps0 = 0.f, pm1 = 0.f, ps1 = 0.f;
    {
        const float4* ag0 = (const float4*)&awgn[(size_t)b0 * L1_];
        const float4* ag1 = (const float4*)&awgn[(size_t)b1 * L1_];
        for (int ii = tid; ii < 1312; ii += 512) {       // 1312*4 = 5248
            float4 a0 = ag0[ii], a1 = ag1[ii];
            int i = ii * 4;
            #pragma unroll
            for (int e = 0; e < 4; ++e) {
                int idx = i + e;
                bool win = (idx >= TSTART_ && idx < TSTART_ + NWIN_);
                float aw0 = (e == 0) ? a0.x : (e == 1) ? a0.y : (e == 2) ? a0.z : a0.w;
                float aw1 = (e == 0) ? a1.x : (e == 1) ? a1.y : (e == 2) ? a1.z : a1.w;
                {
                    float x = dxr[0][SWZ(idx)];
                    float ax = fabsf(x);
                    float over = fmaxf(ax - thr0, 0.f);
                    float y = (1.f - over / (ax + 1e-8f)) * x;
                    if (win) { float p = y * y; ps0 += p; pm0 = fmaxf(pm0, p); }
                    dxr[0][SWZ(idx)] = y + aw0;
                }
                {
                    float x = dxr[1][SWZ(idx)];
                    float ax = fabsf(x);
                    float over = fmaxf(ax - thr1, 0.f);
                    float y = (1.f - over / (ax + 1e-8f)) * x;
                    if (win) { float p = y * y; ps1 += p; pm1 = fmaxf(pm1, p); }
                    dxr[1][SWZ(idx)] = y + aw1;
                }
            }
        }
    }
    ps0 = wave_sum(ps0); pm0 = wave_max(pm0);
    ps1 = wave_sum(ps1); pm1 = wave_max(pm1);
    if (lane == 0) { red[0][wv] = ps0; red2[0][wv] = pm0; red[1][wv] = ps1; red2[1][wv] = pm1; }
    __syncthreads();
    if (tid == 0) {
        float s0 = 0.f, m0 = 0.f, s1 = 0.f, m1 = 0.f;
        #pragma unroll
        for (int w = 0; w < 8; ++w) {
            s0 += red[0][w]; m0 = fmaxf(m0, red2[0][w]);
            s1 += red[1][w]; m1 = fmaxf(m1, red2[1][w]);
        }
        float p0 = 10.f * log10f(m0 / (s0 / (float)NWIN_));
        float p1 = 10.f * log10f(m1 / (s1 / (float)NWIN_));
        papr[b0] = p0; out_papr[b0] = p0;
        papr[b1] = p1; out_papr[b1] = p1;
    }
    __syncthreads();     // all P5 dxr writes visible before P6

    // ---- P6: matched RRC filter -> w~[n] = w[n]*conj(W[n*sloc]) into trti[s*64+n] ----
    {
        int s = wv, n = lane;                            // 8 waves x 64 outputs, both rows
        int T0 = s * 80 + n + 32;                        // Nf/8
        int base = 9 * T0;                               // SWZ(Nf)
        float ar0 = 0.f, ai0 = 0.f, ar1 = 0.f, ai1 = 0.f;
        int db = 0;
        #pragma unroll 4
        for (int e = 0; e < 16; ++e) {
            float4 g01 = *(const float4*)&gcs[db];       // gcs[db], gcs[db+1]
            float4 g23 = *(const float4*)&gcs[db + 2];
            float4 g45 = *(const float4*)&gcs[db + 4];
            float4 g67 = *(const float4*)&gcs[db + 6];
            float gx[8] = { g01.x, g01.z, g23.x, g23.z, g45.x, g45.z, g67.x, g67.z };
            float gy[8] = { g01.y, g01.w, g23.y, g23.w, g45.y, g45.w, g67.y, g67.w };
            #pragma unroll
            for (int u = 0; u < 8; ++u) {
                int off = (u == 0) ? 0 : (u + 1);
                float v0 = dxr[0][base - off];
                float v1 = dxr[1][base - off];
                ar0 += v0 * gx[u]; ai0 += v0 * gy[u];
                ar1 += v1 * gx[u]; ai1 += v1 * gy[u];
            }
            base -= 9; db += 8;
        }
        {
            float2 g = gcs[128];
            float v0 = dxr[0][base], v1 = dxr[1][base];
            ar0 += v0 * g.x; ai0 += v0 * g.y;
            ar1 += v1 * g.x; ai1 += v1 * g.y;
        }
        bool odd = (n & 1);
        float wr0 = odd ? -ar0 : ar0, wi0 = odd ? ai0 : -ai0;
        float wr1 = odd ? -ar1 : ar1, wi1 = odd ? ai1 : -ai1;
        float2 cw = cs64[(n * sloc) & 63];               // w~ = w * conj(W)
        trti[0][s * 64 + n] = make_float2(wr0 * cw.x + wi0 * cw.y, wi0 * cw.x - wr0 * cw.y);
        trti[1][s * 64 + n] = make_float2(wr1 * cw.x + wi1 * cw.y, wi1 * cw.x - wr1 * cw.y);
    }
    __syncthreads();

    // ---- P78: fused DFT64-band-select + IDFT32 via cot identity -> y5b bf16 ----
    {
        int r = tid >> 8, t = tid & 255;
        int s = t >> 5, q = t & 31;
        const float2* wt = &trti[r][s * 64];
        float Wr = 0.f, Wi = 0.f, Ur = 0.f, Ui = 0.f;
        #pragma unroll 4
        for (int u = 0; u < 32; ++u) {
            float2 a = wt[2 * u + 1];
            float w = ct[(2 * q - 2 * u - 1) & 63];
            Wr += a.x; Wi += a.y;
            Ur += a.x * w; Ui += a.y * w;
        }
        float2 e = wt[2 * q];
        float sgn = (q & 1) ? -S2048 : S2048;            // (-1)^q / sqrt2048
        float yr = sgn * (32.f * e.x + Wr - Ui);
        float yi = sgn * (32.f * e.y + Wi + Ur);
        ushort2 h; h.x = bf16_rne(yr); h.y = bf16_rne(yi);
        *(ushort2*)&y5b[(size_t)(b0 + r) * 512 + (s * 32 + q) * 2] = h;
    }
}

extern "C" void kernel_launch(void* const* d_in, const int* in_sizes, int n_in,
                              void* d_out, int out_size, void* d_ws, size_t ws_size,
                              hipStream_t stream) {
    const float* x    = (const float*)d_in[0];
    const float* Wenc = (const float*)d_in[1];
    const float* benc = (const float*)d_in[2];
    const float* Wdec = (const float*)d_in[3];
    const float* bdec = (const float*)d_in[4];
    const float* rrc  = (const float*)d_in[5];
    const float* awgn = (const float*)d_in[6];
    const int* sloc   = (const int*)d_in[7];
    float* out = (float*)d_out;

    char* wsb = (char*)d_ws;
    ushort* w1t  = (ushort*)wsb;                     wsb += (size_t)512 * 3072 * 2;
    ushort* w2t  = (ushort*)wsb;                     wsb += (size_t)3072 * 512 * 2;
    ushort* y5b  = (ushort*)wsb;                     wsb += (size_t)1024 * 512 * 2;
    float*  papr = (float*)wsb;                      wsb += 1024 * 4;
    float*  zbuf = (float*)wsb;                      // partial: 8 x 1024x512 f32 (16.8 MB)
                                                     // fallback: 1024x512 f32 (2.1 MB)
    size_t head = (size_t)((char*)zbuf - (char*)d_ws);
    int partial = (ws_size >= head + (size_t)8 * 1024 * 512 * 4) ? 1 : 0;

    float* out_papr = out + (size_t)1024 * 3072;
    float* out_loss = out_papr + 1024;

    pack_k<<<partial ? 768 : 2816, 256, 0, stream>>>(Wenc, Wdec, benc, w1t, w2t, zbuf);
    gemm1_k<<<dim3(4, 16, 8), 256, 0, stream>>>(x, w1t, zbuf, 1024, 512, 3072, partial);
    mega_k<<<512, 512, 0, stream>>>(zbuf, benc, rrc, awgn, sloc, y5b, papr, out_papr,
                                    partial ? 8 : 0);
    gemm2_k<<<dim3(48, 16, 1), 256, 0, stream>>>(y5b, w2t, bdec, papr, out, out_loss, 1024, 3072, 512);
}